// Round 17
// baseline (208.046 us; speedup 1.0000x reference)
//
#include <hip/hip_runtime.h>

typedef __attribute__((ext_vector_type(8))) short s16x8;
typedef __attribute__((ext_vector_type(4))) short s16x4;
typedef __attribute__((ext_vector_type(4))) float f32x4;

#define SCALE 0.125f
#define LOG2E 1.4426950408889634f
#define QSC (SCALE * LOG2E)

__device__ inline float b2f(unsigned short u) {
    union { unsigned int i; float f; } x; x.i = ((unsigned int)u) << 16; return x.f;
}
__device__ inline unsigned short f2b(float f) {
    union { float f; unsigned int i; } x; x.f = f;
    unsigned int i = x.i;
    unsigned int r = (i + 0x7FFFu + ((i >> 16) & 1u)) >> 16;
    return (unsigned short)r;
}

// async global->LDS, 16B per lane; lds base must be wave-uniform.
typedef const __attribute__((address_space(1))) unsigned int guint;
typedef __attribute__((address_space(3))) unsigned int luint;
__device__ __forceinline__ void gll16(const void* g, void* l) {
    __builtin_amdgcn_global_load_lds((guint*)g, (luint*)l, 16, 0, 0);
}

// counted-vmcnt barrier: allow newest N loads to stay in flight across it.
#define CBAR(N)                                           \
    do {                                                  \
        asm volatile("s_waitcnt vmcnt(" #N ")" ::: "memory"); \
        __builtin_amdgcn_s_barrier();                     \
        asm volatile("" ::: "memory");                    \
    } while (0)

// ================= merged prep kernel (z-task switch) =================
__device__ __forceinline__ void transpose_body(
    const float* __restrict__ in, unsigned short* __restrict__ out,
    int R, int C, unsigned short (*tile)[72]) {
    int tc = blockIdx.x * 64, tr = blockIdx.y * 64;
    int t = threadIdx.x;
    int r = t >> 2, cq = (t & 3) * 16;
    const float* src = in + (size_t)(tr + r) * C + tc + cq;
#pragma unroll
    for (int j = 0; j < 16; j += 4) {
        f32x4 v = *(const f32x4*)(src + j);
        tile[r][cq + j]     = f2b(v[0]);
        tile[r][cq + j + 1] = f2b(v[1]);
        tile[r][cq + j + 2] = f2b(v[2]);
        tile[r][cq + j + 3] = f2b(v[3]);
    }
    __syncthreads();
    int oc = t >> 2, rq = (t & 3) * 16;
    s16x8 w0, w1;
#pragma unroll
    for (int j = 0; j < 8; j++) {
        w0[j] = (short)tile[rq + j][oc];
        w1[j] = (short)tile[rq + 8 + j][oc];
    }
    s16x8* dst = (s16x8*)(out + (size_t)(tc + oc) * R + tr + rq);
    dst[0] = w0; dst[1] = w1;
}

__global__ __launch_bounds__(256) void prep(
    const float* __restrict__ x, const float* __restrict__ R,
    const float* __restrict__ wq, const float* __restrict__ wk,
    const float* __restrict__ wv, const float* __restrict__ wo,
    unsigned short* __restrict__ xb, unsigned short* __restrict__ BTall,
    unsigned short* __restrict__ woT, float* __restrict__ cosT,
    float* __restrict__ sinT) {
    __shared__ unsigned short tile[64][72];
    int z = blockIdx.z;
    if (z == 0) {
        transpose_body(wq, BTall, 2048, 2048, tile);
    } else if (z == 1) {
        transpose_body(wo, woT, 2048, 2048, tile);
    } else if (z == 2) {
        if (blockIdx.x < 8)
            transpose_body(wk, BTall + (size_t)2048 * 2048, 2048, 512, tile);
    } else if (z == 3) {
        if (blockIdx.x < 8)
            transpose_body(wv, BTall + (size_t)2560 * 2048, 2048, 512, tile);
    } else if (z == 4) {
        int bid = blockIdx.y * 32 + blockIdx.x;
        int i = (bid * 256 + threadIdx.x) * 16;
#pragma unroll
        for (int half = 0; half < 2; half++) {
            int ii = i + half * 8;
            f32x4 a = *(const f32x4*)(x + ii);
            f32x4 b = *(const f32x4*)(x + ii + 4);
            s16x8 o;
            o[0] = (short)f2b(a[0]); o[1] = (short)f2b(a[1]);
            o[2] = (short)f2b(a[2]); o[3] = (short)f2b(a[3]);
            o[4] = (short)f2b(b[0]); o[5] = (short)f2b(b[1]);
            o[6] = (short)f2b(b[2]); o[7] = (short)f2b(b[3]);
            *(s16x8*)(xb + ii) = o;
        }
    } else {
        int bid = blockIdx.y * 32 + blockIdx.x;
        if (bid < 256) {
            int idx = bid * 256 + threadIdx.x;  // L*32
            int l = idx >> 5, i = idx & 31;
            size_t base = (size_t)l * 4096;
            cosT[idx] = R[base + (size_t)(2 * i) * 64 + 2 * i];
            sinT[idx] = R[base + (size_t)(2 * i + 1) * 64 + 2 * i];
        }
    }
}

// ==== GEMM core v6 (B-direct hybrid): 128x128 tile, 4 waves (2x2), 4x4
// acc. r16 diagnosis: LDS bandwidth bound (48KB/block-iter = ~100% of the
// 128B/cy port). B-fragments now load straight from global into registers
// (double-buffered 1 K-step ahead; panels L2-resident via XCD swizzle) —
// LDS carries only A: 24KB/block-iter (halved). CBAR(6) = 4 B-loads + 2
// A-stages in flight. Source preswizzle + swizzled reads for A unchanged.

// ---- fused QKV GEMM + RoPE epilogue (+ K/V f32 outputs, V^T bf16) ----
__global__ __launch_bounds__(256) void gemm_qkv(
    const unsigned short* __restrict__ A, const unsigned short* __restrict__ BT,
    unsigned short* __restrict__ Qb, unsigned short* __restrict__ Kb,
    unsigned short* __restrict__ VtT, const float* __restrict__ cosT,
    const float* __restrict__ sinT, float* __restrict__ outK,
    float* __restrict__ outV) {
    const int K = 2048;
    __shared__ unsigned short As[3][128 * 32];
    int t = threadIdx.x;
    int w = t >> 6, lane = t & 63, lo = lane & 15, hi = lane >> 4;
    // XCD-chunked swizzle: 384 blocks, 48/XCD chunk = all 16 m x 3 n.
    int bid = blockIdx.x;
    int lid = (bid & 7) * 48 + (bid >> 3);
    int m0 = (lid & 15) * 128, n0 = (lid >> 4) * 128;
    int wr = w >> 1, wc = w & 1;
    int sr = lane >> 2;
    int scol = ((lane & 3) ^ (sr & 3)) * 8;  // preswizzled source chunk
    int rsw = (hi ^ (lo & 3)) * 8;           // swizzled read chunk

    const unsigned short* gA = A + (size_t)(m0 + w * 16 + sr) * K + scol;
    const unsigned short* gBd = BT + (size_t)(n0 + wc * 64 + lo) * K + hi * 8;

#define ASTAGE(buf, kk)                                                   \
    {                                                                     \
        gll16(gA + (kk), &As[buf][(w * 16) * 32]);                        \
        gll16(gA + (size_t)64 * K + (kk), &As[buf][(64 + w * 16) * 32]);  \
    }
#define BLOAD(dst, kk)                                                    \
    {                                                                     \
        _Pragma("unroll")                                                 \
        for (int j = 0; j < 4; j++)                                       \
            dst[j] = *(const s16x8*)(gBd + (size_t)(j * 16) * K + (kk));  \
    }

    f32x4 acc[4][4] = {};
    s16x8 bcur[4], bnxt[4];

    ASTAGE(0, 0);
    ASTAGE(1, 32);
    BLOAD(bcur, 0);
    int cur = 0, sb = 2;

    for (int k0 = 0; k0 < K; k0 += 32) {
        if (k0 + 32 < K) BLOAD(bnxt, k0 + 32);
        if (k0 + 64 < K) {
            CBAR(6);
            ASTAGE(sb, k0 + 64);
        } else if (k0 + 32 < K) {
            CBAR(6);
        } else {
            CBAR(0);
        }
        s16x8 af[4];
#pragma unroll
        for (int i = 0; i < 4; i++)
            af[i] = *(const s16x8*)&As[cur][(wr * 64 + i * 16 + lo) * 32 + rsw];
#pragma unroll
        for (int i = 0; i < 4; i++)
#pragma unroll
            for (int j = 0; j < 4; j++)
                acc[i][j] = __builtin_amdgcn_mfma_f32_16x16x32_bf16(
                    af[i], bcur[j], acc[i][j], 0, 0, 0);
#pragma unroll
        for (int j = 0; j < 4; j++) bcur[j] = bnxt[j];
        cur = (cur == 2) ? 0 : cur + 1;
        sb = (sb == 2) ? 0 : sb + 1;
    }

    if (n0 < 2048) {  // ---- Q: rope + QSC ----
#pragma unroll
        for (int i = 0; i < 4; i++)
#pragma unroll
            for (int j = 0; j < 4; j++) {
                int colb = n0 + wc * 64 + j * 16 + lo;
                int d = colb & 63;
                float sgn = (d & 1) ? 1.0f : -1.0f;
                int ip = d >> 1;
#pragma unroll
                for (int r = 0; r < 4; r++) {
                    int row = m0 + wr * 64 + i * 16 + hi * 4 + r;
                    float v = acc[i][j][r];
                    float p = __shfl_xor(v, 1);
                    float c = cosT[row * 32 + ip], s = sinT[row * 32 + ip];
                    float o = (c * v + sgn * s * p) * QSC;
                    Qb[(size_t)row * 2048 + colb] = f2b(o);
                }
            }
    } else if (n0 < 2560) {  // ---- K: rope + repeated f32 out ----
        int cb = n0 - 2048;
#pragma unroll
        for (int i = 0; i < 4; i++)
#pragma unroll
            for (int j = 0; j < 4; j++) {
                int colb = cb + wc * 64 + j * 16 + lo;
                int d = colb & 63;
                int kvh2 = colb >> 6;
                float sgn = (d & 1) ? 1.0f : -1.0f;
                int ip = d >> 1;
#pragma unroll
                for (int r = 0; r < 4; r++) {
                    int row = m0 + wr * 64 + i * 16 + hi * 4 + r;
                    float v = acc[i][j][r];
                    float p = __shfl_xor(v, 1);
                    float c = cosT[row * 32 + ip], s = sinT[row * 32 + ip];
                    float o = c * v + sgn * s * p;
                    Kb[(size_t)row * 512 + colb] = f2b(o);
#pragma unroll
                    for (int rep = 0; rep < 4; rep++) {
                        int h2 = kvh2 * 4 + rep;
                        outK[((size_t)h2 * 2048 + row) * 64 + d] = o;
                    }
                }
            }
    } else {  // ---- V: V^T bf16 (for attn) + repeated f32 out ----
        int cb = n0 - 2560;
#pragma unroll
        for (int i = 0; i < 4; i++)
#pragma unroll
            for (int j = 0; j < 4; j++) {
                int colb = cb + wc * 64 + j * 16 + lo;
                int d = colb & 63;
                int kvh2 = colb >> 6;
                int row0 = m0 + wr * 64 + i * 16 + hi * 4;
                s16x4 vv;
#pragma unroll
                for (int r = 0; r < 4; r++) {
                    int row = row0 + r;
                    float v = acc[i][j][r];
                    vv[r] = (short)f2b(v);
#pragma unroll
                    for (int rep = 0; rep < 4; rep++) {
                        int h2 = kvh2 * 4 + rep;
                        outV[((size_t)h2 * 2048 + row) * 64 + d] = v;
                    }
                }
                *(s16x4*)&VtT[(size_t)colb * 2048 + row0] = vv;
            }
    }
#undef ASTAGE
#undef BLOAD
}

// -------- output GEMM (B-direct): 128x128, 4 waves, 256 blocks --------
__global__ __launch_bounds__(256) void gemm_out(
    const unsigned short* __restrict__ A, const unsigned short* __restrict__ BT,
    float* __restrict__ C) {
    const int K = 2048, N = 2048;
    __shared__ unsigned short As[3][128 * 32];
    int t = threadIdx.x;
    int w = t >> 6, lane = t & 63, lo = lane & 15, hi = lane >> 4;
    // XCD-chunked: 256 blocks = 8 XCD x (16 m x 2 n), m fastest.
    int bid = blockIdx.x;
    int lid = (bid & 7) * 32 + (bid >> 3);
    int m0 = (lid & 15) * 128, n0 = (lid >> 4) * 128;
    int wr = w >> 1, wc = w & 1;
    int sr = lane >> 2;
    int scol = ((lane & 3) ^ (sr & 3)) * 8;
    int rsw = (hi ^ (lo & 3)) * 8;

    const unsigned short* gA = A + (size_t)(m0 + w * 16 + sr) * K + scol;
    const unsigned short* gBd = BT + (size_t)(n0 + wc * 64 + lo) * K + hi * 8;

#define ASTAGE(buf, kk)                                                   \
    {                                                                     \
        gll16(gA + (kk), &As[buf][(w * 16) * 32]);                        \
        gll16(gA + (size_t)64 * K + (kk), &As[buf][(64 + w * 16) * 32]);  \
    }
#define BLOAD(dst, kk)                                                    \
    {                                                                     \
        _Pragma("unroll")                                                 \
        for (int j = 0; j < 4; j++)                                       \
            dst[j] = *(const s16x8*)(gBd + (size_t)(j * 16) * K + (kk));  \
    }

    f32x4 acc[4][4] = {};
    s16x8 bcur[4], bnxt[4];

    ASTAGE(0, 0);
    ASTAGE(1, 32);
    BLOAD(bcur, 0);
    int cur = 0, sb = 2;

    for (int k0 = 0; k0 < K; k0 += 32) {
        if (k0 + 32 < K) BLOAD(bnxt, k0 + 32);
        if (k0 + 64 < K) {
            CBAR(6);
            ASTAGE(sb, k0 + 64);
        } else if (k0 + 32 < K) {
            CBAR(6);
        } else {
            CBAR(0);
        }
        s16x8 af[4];
#pragma unroll
        for (int i = 0; i < 4; i++)
            af[i] = *(const s16x8*)&As[cur][(wr * 64 + i * 16 + lo) * 32 + rsw];
#pragma unroll
        for (int i = 0; i < 4; i++)
#pragma unroll
            for (int j = 0; j < 4; j++)
                acc[i][j] = __builtin_amdgcn_mfma_f32_16x16x32_bf16(
                    af[i], bcur[j], acc[i][j], 0, 0, 0);
#pragma unroll
        for (int j = 0; j < 4; j++) bcur[j] = bnxt[j];
        cur = (cur == 2) ? 0 : cur + 1;
        sb = (sb == 2) ? 0 : sb + 1;
    }
#pragma unroll
    for (int i = 0; i < 4; i++)
#pragma unroll
        for (int j = 0; j < 4; j++)
#pragma unroll
            for (int r = 0; r < 4; r++) {
                int row = m0 + wr * 64 + i * 16 + hi * 4 + r;
                int col = n0 + wc * 64 + j * 16 + lo;
                C[(size_t)row * N + col] = acc[i][j][r];
            }
#undef ASTAGE
#undef BLOAD
}

// ====================== flash attention (causal) ======================
// (unchanged — 512 equal blocks, verified)

__device__ __forceinline__ s16x8 repack_p(
    const unsigned int pk[4][2], int c, int src1, bool selB) {
    int src2 = src1 + 16;
    unsigned int tA0 = pk[2 * c][0], tA1 = pk[2 * c][1];
    unsigned int tB0 = pk[2 * c + 1][0], tB1 = pk[2 * c + 1][1];
    unsigned int a0 = __shfl((int)tA0, src1), a1 = __shfl((int)tA1, src1);
    unsigned int a2 = __shfl((int)tA0, src2), a3 = __shfl((int)tA1, src2);
    unsigned int b0 = __shfl((int)tB0, src1), b1 = __shfl((int)tB1, src1);
    unsigned int b2 = __shfl((int)tB0, src2), b3 = __shfl((int)tB1, src2);
    union { s16x8 v; unsigned int u[4]; } x;
    x.u[0] = selB ? b0 : a0;
    x.u[1] = selB ? b1 : a1;
    x.u[2] = selB ? b2 : a2;
    x.u[3] = selB ? b3 : a3;
    return x.v;
}

__global__ __launch_bounds__(256) void attn(
    const unsigned short* __restrict__ Q, const unsigned short* __restrict__ Kr,
    const unsigned short* __restrict__ Vt, unsigned short* __restrict__ Oa) {
    __shared__ unsigned short KL[3][64 * 64];
    __shared__ unsigned short VL[3][64 * 64];

    int h = blockIdx.x;
    int kvh = h >> 2;
    int p = blockIdx.y;  // 0..15 -> strips (p, 31-p)
    int t = threadIdx.x, wave = t >> 6, lane = t & 63, lo = lane & 15, hi = lane >> 4;

    int srow = wave * 16 + (lane >> 3);
    int sc = lane & 7;
    int src1 = lo + ((hi & 1) << 5);
    bool selB = hi >= 2;
    int swz = lo & 7;
    int qrel = wave * 16 + lo;

#define STAGE_KV(buf, kb)                                                          \
    {                                                                              \
        _Pragma("unroll")                                                          \
        for (int j = 0; j < 2; j++) {                                              \
            int r = srow + j * 8;                                                  \
            gll16(Kr + (size_t)((kb) * 64 + r) * 512 + kvh * 64 +                  \
                      ((sc ^ (r & 7)) * 8),                                        \
                  &KL[buf][(wave * 16 + j * 8) * 64]);                             \
            gll16(Vt + (size_t)(kvh * 64 + r) * 2048 + (kb) * 64 +                 \
                      ((sc ^ (r & 7)) * 8),                                        \
                  &VL[buf][(wave * 16 + j * 8) * 64]);                             \
        }                                                                          \
    }

#pragma unroll 1
    for (int part = 0; part < 2; ++part) {
        int s = part ? (31 - p) : p;
        int qw = s * 64 + wave * 16;

        s16x8 qf[2];
#pragma unroll
        for (int hf = 0; hf < 2; hf++)
            qf[hf] = *(const s16x8*)(Q + (size_t)(qw + lo) * 2048 +
                                     h * 64 + hf * 32 + hi * 8);

        f32x4 O[4] = {};
        float m = -1e30f, l = 0.f;

        STAGE_KV(0, 0);
        STAGE_KV(1, (s > 0 ? 1 : 0));
        int cur = 0, sb = 2;

        for (int kb = 0; kb <= s; ++kb) {
            CBAR(4);
            int nx = (kb + 2 > s) ? s : kb + 2;
            STAGE_KV(sb, nx);

            s16x8 kf[4][2];
#pragma unroll
            for (int tt = 0; tt < 4; tt++)
#pragma unroll
                for (int hf = 0; hf < 2; hf++) {
                    int ch = (hf * 4 + hi) ^ swz;
                    kf[tt][hf] = *(const s16x8*)&KL[cur][(tt * 16 + lo) * 64 + ch * 8];
                }
            s16x8 vf[2][4];
#pragma unroll
            for (int c = 0; c < 2; c++)
#pragma unroll
                for (int dt = 0; dt < 4; dt++) {
                    int ch = (c * 4 + hi) ^ swz;
                    vf[c][dt] = *(const s16x8*)&VL[cur][(dt * 16 + lo) * 64 + ch * 8];
                }

            f32x4 s0[4];
            __builtin_amdgcn_s_setprio(1);
#pragma unroll
            for (int tt = 0; tt < 4; tt++) {
                f32x4 z0 = {};
                z0 = __builtin_amdgcn_mfma_f32_16x16x32_bf16(kf[tt][0], qf[0], z0, 0, 0, 0);
                z0 = __builtin_amdgcn_mfma_f32_16x16x32_bf16(kf[tt][1], qf[1], z0, 0, 0, 0);
                s0[tt] = z0;
            }
            __builtin_amdgcn_s_setprio(0);

            if (kb == s) {
#pragma unroll
                for (int tt = 0; tt < 4; tt++)
#pragma unroll
                    for (int r = 0; r < 4; r++) {
                        int kg = tt * 16 + hi * 4 + r;
                        if (kg > qrel) s0[tt][r] = -1e30f;
                    }
            }

            float mx = s0[0][0];
#pragma unroll
            for (int tt = 0; tt < 4; tt++)
#pragma unroll
                for (int r = 0; r < 4; r++) mx = fmaxf(mx, s0[tt][r]);
            mx = fmaxf(mx, __shfl_xor(mx, 16));
            mx = fmaxf(mx, __shfl_xor(mx, 32));

            if (!__all(mx - m <= 8.0f)) {
                float mn = fmaxf(m, mx);
                float al = __builtin_amdgcn_exp2f(m - mn);
                m = mn;
                l *= al;
                float alr[4];
#pragma unroll
                for (int r = 0; r < 4; r++) alr[r] = __shfl(al, hi * 4 + r);
#pragma unroll
                for (int dt = 0; dt < 4; dt++)
#pragma unroll
                    for (int r = 0; r < 4; r++) O[dt][r] *= alr[r];
            }

            unsigned int pk[4][2];
            float rs = 0.f;
#pragma unroll
            for (int tt = 0; tt < 4; tt++) {
#pragma unroll
                for (int r = 0; r < 4; r++) {
                    float pv = __builtin_amdgcn_exp2f(s0[tt][r] - m);
                    s0[tt][r] = pv;
                    rs += pv;
                }
                unsigned int a, b;
                asm("v_cvt_pk_bf16_f32 %0, %1, %2" : "=v"(a) : "v"(s0[tt][0]), "v"(s0[tt][1]));
                asm("v_cvt_pk_bf16_f32 %0, %1, %2" : "=v"(b) : "v"(s0[tt][2]), "v"(s0[tt][3]));
                pk[tt][0] = a; pk[tt][1] = b;
            }
            rs += __shfl_xor(rs, 16);
            rs += __shfl_xor(rs, 32);
            l += rs;

#pragma unroll
            for (int c = 0; c < 2; c++) {
                s16x8 pa = repack_p(pk, c, src1, selB);
                __builtin_amdgcn_s_setprio(1);
#pragma unroll
                for (int dt = 0; dt < 4; dt++)
                    O[dt] = __builtin_amdgcn_mfma_f32_16x16x32_bf16(pa, vf[c][dt], O[dt], 0, 0, 0);
                __builtin_amdgcn_s_setprio(0);
            }

            cur = (cur == 2) ? 0 : cur + 1;
            sb = (sb == 2) ? 0 : sb + 1;
        }

        asm volatile("s_waitcnt vmcnt(0)" ::: "memory");
        __builtin_amdgcn_s_barrier();
        asm volatile("" ::: "memory");

        float inv[4];
#pragma unroll
        for (int r = 0; r < 4; r++) inv[r] = 1.0f / __shfl(l, hi * 4 + r);
        int qrow = qw + hi * 4;
#pragma unroll
        for (int dt = 0; dt < 4; dt++)
#pragma unroll
            for (int r = 0; r < 4; r++)
                Oa[(size_t)(qrow + r) * 2048 + h * 64 + dt * 16 + lo] =
                    f2b(O[dt][r] * inv[r]);
    }
}

extern "C" void kernel_launch(void* const* d_in, const int* in_sizes, int n_in,
                              void* d_out, int out_size, void* d_ws, size_t ws_size,
                              hipStream_t stream) {
    const float* x  = (const float*)d_in[0];
    const float* R  = (const float*)d_in[1];
    // d_in[2] = mask: unused (causal mask applied analytically)
    const float* wq = (const float*)d_in[3];
    const float* wk = (const float*)d_in[4];
    const float* wv = (const float*)d_in[5];
    const float* wo = (const float*)d_in[6];

    float* out0 = (float*)d_out;
    float* outK = out0 + (size_t)2048 * 2048;
    float* outV = outK + (size_t)32 * 2048 * 64;

    char* ws = (char*)d_ws;
    unsigned short* BTall = (unsigned short*)(ws);               // 12 MB [3072][2048]
    unsigned short* woT = (unsigned short*)(ws + 12582912);      // 8 MB
    unsigned short* Qb  = (unsigned short*)(ws + 20971520);      // 8 MB
    unsigned short* Kb  = (unsigned short*)(ws + 29360128);      // 2 MB
    unsigned short* VtT = (unsigned short*)(ws + 33554432);      // 2 MB [512][2048]
    unsigned short* Ob  = (unsigned short*)(ws + 35651584);      // 8 MB
    float* cosT = (float*)(ws + 44040192);                       // 256 KB
    float* sinT = (float*)(ws + 44302336);                       // 256 KB
    unsigned short* xb  = (unsigned short*)(ws + 44564480);      // 8 MB

    prep<<<dim3(32, 32, 6), 256, 0, stream>>>(x, R, wq, wk, wv, wo, xb, BTall,
                                              woT, cosT, sinT);

    gemm_qkv<<<384, 256, 0, stream>>>(xb, BTall, Qb, Kb, VtT, cosT, sinT, outK, outV);

    attn<<<dim3(32, 16), 256, 0, stream>>>(Qb, Kb, VtT, Ob);

    gemm_out<<<256, 256, 0, stream>>>(Ob, woT, out0);
}

// Round 18
// 160.467 us; speedup vs baseline: 1.2965x; 1.2965x over previous
//
#include <hip/hip_runtime.h>

typedef __attribute__((ext_vector_type(8))) short s16x8;
typedef __attribute__((ext_vector_type(4))) short s16x4;
typedef __attribute__((ext_vector_type(4))) float f32x4;

#define SCALE 0.125f
#define LOG2E 1.4426950408889634f
#define QSC (SCALE * LOG2E)

__device__ inline float b2f(unsigned short u) {
    union { unsigned int i; float f; } x; x.i = ((unsigned int)u) << 16; return x.f;
}
__device__ inline unsigned short f2b(float f) {
    union { float f; unsigned int i; } x; x.f = f;
    unsigned int i = x.i;
    unsigned int r = (i + 0x7FFFu + ((i >> 16) & 1u)) >> 16;
    return (unsigned short)r;
}

// async global->LDS, 16B per lane; lds base must be wave-uniform.
typedef const __attribute__((address_space(1))) unsigned int guint;
typedef __attribute__((address_space(3))) unsigned int luint;
__device__ __forceinline__ void gll16(const void* g, void* l) {
    __builtin_amdgcn_global_load_lds((guint*)g, (luint*)l, 16, 0, 0);
}

// counted-vmcnt barrier: allow newest N loads to stay in flight across it.
#define CBAR(N)                                           \
    do {                                                  \
        asm volatile("s_waitcnt vmcnt(" #N ")" ::: "memory"); \
        __builtin_amdgcn_s_barrier();                     \
        asm volatile("" ::: "memory");                    \
    } while (0)

// ================= merged prep kernel (z-task switch) =================
__device__ __forceinline__ void transpose_body(
    const float* __restrict__ in, unsigned short* __restrict__ out,
    int R, int C, unsigned short (*tile)[72]) {
    int tc = blockIdx.x * 64, tr = blockIdx.y * 64;
    int t = threadIdx.x;
    int r = t >> 2, cq = (t & 3) * 16;
    const float* src = in + (size_t)(tr + r) * C + tc + cq;
#pragma unroll
    for (int j = 0; j < 16; j += 4) {
        f32x4 v = *(const f32x4*)(src + j);
        tile[r][cq + j]     = f2b(v[0]);
        tile[r][cq + j + 1] = f2b(v[1]);
        tile[r][cq + j + 2] = f2b(v[2]);
        tile[r][cq + j + 3] = f2b(v[3]);
    }
    __syncthreads();
    int oc = t >> 2, rq = (t & 3) * 16;
    s16x8 w0, w1;
#pragma unroll
    for (int j = 0; j < 8; j++) {
        w0[j] = (short)tile[rq + j][oc];
        w1[j] = (short)tile[rq + 8 + j][oc];
    }
    s16x8* dst = (s16x8*)(out + (size_t)(tc + oc) * R + tr + rq);
    dst[0] = w0; dst[1] = w1;
}

__global__ __launch_bounds__(256) void prep(
    const float* __restrict__ x, const float* __restrict__ R,
    const float* __restrict__ wq, const float* __restrict__ wk,
    const float* __restrict__ wv, const float* __restrict__ wo,
    unsigned short* __restrict__ xb, unsigned short* __restrict__ BTall,
    unsigned short* __restrict__ woT, float* __restrict__ cosT,
    float* __restrict__ sinT) {
    __shared__ unsigned short tile[64][72];
    int z = blockIdx.z;
    if (z == 0) {
        transpose_body(wq, BTall, 2048, 2048, tile);
    } else if (z == 1) {
        transpose_body(wo, woT, 2048, 2048, tile);
    } else if (z == 2) {
        if (blockIdx.x < 8)
            transpose_body(wk, BTall + (size_t)2048 * 2048, 2048, 512, tile);
    } else if (z == 3) {
        if (blockIdx.x < 8)
            transpose_body(wv, BTall + (size_t)2560 * 2048, 2048, 512, tile);
    } else if (z == 4) {
        int bid = blockIdx.y * 32 + blockIdx.x;
        int i = (bid * 256 + threadIdx.x) * 16;
#pragma unroll
        for (int half = 0; half < 2; half++) {
            int ii = i + half * 8;
            f32x4 a = *(const f32x4*)(x + ii);
            f32x4 b = *(const f32x4*)(x + ii + 4);
            s16x8 o;
            o[0] = (short)f2b(a[0]); o[1] = (short)f2b(a[1]);
            o[2] = (short)f2b(a[2]); o[3] = (short)f2b(a[3]);
            o[4] = (short)f2b(b[0]); o[5] = (short)f2b(b[1]);
            o[6] = (short)f2b(b[2]); o[7] = (short)f2b(b[3]);
            *(s16x8*)(xb + ii) = o;
        }
    } else {
        int bid = blockIdx.y * 32 + blockIdx.x;
        if (bid < 256) {
            int idx = bid * 256 + threadIdx.x;  // L*32
            int l = idx >> 5, i = idx & 31;
            size_t base = (size_t)l * 4096;
            cosT[idx] = R[base + (size_t)(2 * i) * 64 + 2 * i];
            sinT[idx] = R[base + (size_t)(2 * i + 1) * 64 + 2 * i];
        }
    }
}

// ==== GEMM core (r12 best-measured): 64(M) x 128(N) tile, 2 waves,
// 64x64 per wave (4x4 acc). 3 LDS buffers, stage-2-ahead, CBAR(6).
// Linear LDS dest + XOR-preswizzled global source chunk; reads apply the
// same XOR. (Rounds 13-17 established this family's ~60us plateau; this
// is the best-total configuration, restored.)

// ---- fused QKV GEMM + RoPE epilogue (+ K/V f32 outputs, V^T bf16) ----
__global__ __launch_bounds__(128) void gemm_qkv(
    const unsigned short* __restrict__ A, const unsigned short* __restrict__ BT,
    unsigned short* __restrict__ Qb, unsigned short* __restrict__ Kb,
    unsigned short* __restrict__ VtT, const float* __restrict__ cosT,
    const float* __restrict__ sinT, float* __restrict__ outK,
    float* __restrict__ outV) {
    const int K = 2048;
    __shared__ unsigned short As[3][64 * 32];
    __shared__ unsigned short Bs[3][128 * 32];
    int t = threadIdx.x;
    int w = t >> 6, lane = t & 63, lo = lane & 15, hi = lane >> 4;
    int m0 = blockIdx.y * 64, n0 = blockIdx.x * 128;
    int sr = lane >> 2;                      // row within 16-row gll block
    int scol = ((lane & 3) ^ (sr & 3)) * 8;  // preswizzled source chunk

    const unsigned short* gA = A + (size_t)(m0 + w * 32 + sr) * K + scol;
    const unsigned short* gB = BT + (size_t)(n0 + w * 64 + sr) * K + scol;
    int rsw = (hi ^ (lo & 3)) * 8;           // swizzled read chunk

#define GSTAGE(buf, kk)                                                   \
    {                                                                     \
        gll16(gA + (kk), &As[buf][(w * 32) * 32]);                        \
        gll16(gA + (size_t)16 * K + (kk), &As[buf][(w * 32 + 16) * 32]);  \
        gll16(gB + (kk), &Bs[buf][(w * 64) * 32]);                        \
        gll16(gB + (size_t)16 * K + (kk), &Bs[buf][(w * 64 + 16) * 32]);  \
        gll16(gB + (size_t)32 * K + (kk), &Bs[buf][(w * 64 + 32) * 32]);  \
        gll16(gB + (size_t)48 * K + (kk), &Bs[buf][(w * 64 + 48) * 32]);  \
    }

    f32x4 acc[4][4] = {};

    GSTAGE(0, 0);
    GSTAGE(1, 32);
    int cur = 0, sb = 2;

    for (int k0 = 0; k0 < K; k0 += 32) {
        if (k0 + 64 < K) {
            CBAR(6);
            GSTAGE(sb, k0 + 64);
        } else if (k0 + 32 < K) {
            CBAR(6);
        } else {
            CBAR(0);
        }
        s16x8 af[4], bfr[4];
#pragma unroll
        for (int i = 0; i < 4; i++)
            af[i] = *(const s16x8*)&As[cur][(i * 16 + lo) * 32 + rsw];
#pragma unroll
        for (int j = 0; j < 4; j++)
            bfr[j] = *(const s16x8*)&Bs[cur][(w * 64 + j * 16 + lo) * 32 + rsw];
#pragma unroll
        for (int i = 0; i < 4; i++)
#pragma unroll
            for (int j = 0; j < 4; j++)
                acc[i][j] = __builtin_amdgcn_mfma_f32_16x16x32_bf16(
                    af[i], bfr[j], acc[i][j], 0, 0, 0);
        cur = (cur == 2) ? 0 : cur + 1;
        sb = (sb == 2) ? 0 : sb + 1;
    }

    if (n0 < 2048) {  // ---- Q: rope + QSC ----
#pragma unroll
        for (int i = 0; i < 4; i++)
#pragma unroll
            for (int j = 0; j < 4; j++) {
                int colb = n0 + w * 64 + j * 16 + lo;
                int d = colb & 63;
                float sgn = (d & 1) ? 1.0f : -1.0f;
                int ip = d >> 1;
#pragma unroll
                for (int r = 0; r < 4; r++) {
                    int row = m0 + i * 16 + hi * 4 + r;
                    float v = acc[i][j][r];
                    float p = __shfl_xor(v, 1);
                    float c = cosT[row * 32 + ip], s = sinT[row * 32 + ip];
                    float o = (c * v + sgn * s * p) * QSC;
                    Qb[(size_t)row * 2048 + colb] = f2b(o);
                }
            }
    } else if (n0 < 2560) {  // ---- K: rope + repeated f32 out ----
        int cb = n0 - 2048;
#pragma unroll
        for (int i = 0; i < 4; i++)
#pragma unroll
            for (int j = 0; j < 4; j++) {
                int colb = cb + w * 64 + j * 16 + lo;
                int d = colb & 63;
                int kvh2 = colb >> 6;
                float sgn = (d & 1) ? 1.0f : -1.0f;
                int ip = d >> 1;
#pragma unroll
                for (int r = 0; r < 4; r++) {
                    int row = m0 + i * 16 + hi * 4 + r;
                    float v = acc[i][j][r];
                    float p = __shfl_xor(v, 1);
                    float c = cosT[row * 32 + ip], s = sinT[row * 32 + ip];
                    float o = c * v + sgn * s * p;
                    Kb[(size_t)row * 512 + colb] = f2b(o);
#pragma unroll
                    for (int rep = 0; rep < 4; rep++) {
                        int h2 = kvh2 * 4 + rep;
                        outK[((size_t)h2 * 2048 + row) * 64 + d] = o;
                    }
                }
            }
    } else {  // ---- V: V^T bf16 (for attn) + repeated f32 out ----
        int cb = n0 - 2560;
#pragma unroll
        for (int i = 0; i < 4; i++)
#pragma unroll
            for (int j = 0; j < 4; j++) {
                int colb = cb + w * 64 + j * 16 + lo;
                int d = colb & 63;
                int kvh2 = colb >> 6;
                int row0 = m0 + i * 16 + hi * 4;
                s16x4 vv;
#pragma unroll
                for (int r = 0; r < 4; r++) {
                    int row = row0 + r;
                    float v = acc[i][j][r];
                    vv[r] = (short)f2b(v);
#pragma unroll
                    for (int rep = 0; rep < 4; rep++) {
                        int h2 = kvh2 * 4 + rep;
                        outV[((size_t)h2 * 2048 + row) * 64 + d] = v;
                    }
                }
                *(s16x4*)&VtT[(size_t)colb * 2048 + row0] = vv;
            }
    }
#undef GSTAGE
}

// -------- output GEMM (r12): A[M][K] bf16, BT[N][K] bf16 -> C f32 --------
__global__ __launch_bounds__(128) void gemm_out(
    const unsigned short* __restrict__ A, const unsigned short* __restrict__ BT,
    float* __restrict__ C, int M, int N, int K) {
    __shared__ unsigned short As[3][64 * 32];
    __shared__ unsigned short Bs[3][128 * 32];
    int t = threadIdx.x;
    int w = t >> 6, lane = t & 63, lo = lane & 15, hi = lane >> 4;
    int m0 = blockIdx.y * 64, n0 = blockIdx.x * 128;
    int sr = lane >> 2;
    int scol = ((lane & 3) ^ (sr & 3)) * 8;

    const unsigned short* gA = A + (size_t)(m0 + w * 32 + sr) * K + scol;
    const unsigned short* gB = BT + (size_t)(n0 + w * 64 + sr) * K + scol;
    int rsw = (hi ^ (lo & 3)) * 8;

#define GSTAGE(buf, kk)                                                   \
    {                                                                     \
        gll16(gA + (kk), &As[buf][(w * 32) * 32]);                        \
        gll16(gA + (size_t)16 * K + (kk), &As[buf][(w * 32 + 16) * 32]);  \
        gll16(gB + (kk), &Bs[buf][(w * 64) * 32]);                        \
        gll16(gB + (size_t)16 * K + (kk), &Bs[buf][(w * 64 + 16) * 32]);  \
        gll16(gB + (size_t)32 * K + (kk), &Bs[buf][(w * 64 + 32) * 32]);  \
        gll16(gB + (size_t)48 * K + (kk), &Bs[buf][(w * 64 + 48) * 32]);  \
    }

    f32x4 acc[4][4] = {};

    GSTAGE(0, 0);
    GSTAGE(1, 32);
    int cur = 0, sb = 2;

    for (int k0 = 0; k0 < K; k0 += 32) {
        if (k0 + 64 < K) {
            CBAR(6);
            GSTAGE(sb, k0 + 64);
        } else if (k0 + 32 < K) {
            CBAR(6);
        } else {
            CBAR(0);
        }
        s16x8 af[4], bfr[4];
#pragma unroll
        for (int i = 0; i < 4; i++)
            af[i] = *(const s16x8*)&As[cur][(i * 16 + lo) * 32 + rsw];
#pragma unroll
        for (int j = 0; j < 4; j++)
            bfr[j] = *(const s16x8*)&Bs[cur][(w * 64 + j * 16 + lo) * 32 + rsw];
#pragma unroll
        for (int i = 0; i < 4; i++)
#pragma unroll
            for (int j = 0; j < 4; j++)
                acc[i][j] = __builtin_amdgcn_mfma_f32_16x16x32_bf16(
                    af[i], bfr[j], acc[i][j], 0, 0, 0);
        cur = (cur == 2) ? 0 : cur + 1;
        sb = (sb == 2) ? 0 : sb + 1;
    }
#pragma unroll
    for (int i = 0; i < 4; i++)
#pragma unroll
        for (int j = 0; j < 4; j++)
#pragma unroll
            for (int r = 0; r < 4; r++) {
                int row = m0 + i * 16 + hi * 4 + r;
                int col = n0 + w * 64 + j * 16 + lo;
                C[(size_t)row * N + col] = acc[i][j][r];
            }
#undef GSTAGE
}

// ====================== flash attention (causal) ======================
// (unchanged — 512 equal blocks, verified)

__device__ __forceinline__ s16x8 repack_p(
    const unsigned int pk[4][2], int c, int src1, bool selB) {
    int src2 = src1 + 16;
    unsigned int tA0 = pk[2 * c][0], tA1 = pk[2 * c][1];
    unsigned int tB0 = pk[2 * c + 1][0], tB1 = pk[2 * c + 1][1];
    unsigned int a0 = __shfl((int)tA0, src1), a1 = __shfl((int)tA1, src1);
    unsigned int a2 = __shfl((int)tA0, src2), a3 = __shfl((int)tA1, src2);
    unsigned int b0 = __shfl((int)tB0, src1), b1 = __shfl((int)tB1, src1);
    unsigned int b2 = __shfl((int)tB0, src2), b3 = __shfl((int)tB1, src2);
    union { s16x8 v; unsigned int u[4]; } x;
    x.u[0] = selB ? b0 : a0;
    x.u[1] = selB ? b1 : a1;
    x.u[2] = selB ? b2 : a2;
    x.u[3] = selB ? b3 : a3;
    return x.v;
}

__global__ __launch_bounds__(256) void attn(
    const unsigned short* __restrict__ Q, const unsigned short* __restrict__ Kr,
    const unsigned short* __restrict__ Vt, unsigned short* __restrict__ Oa) {
    __shared__ unsigned short KL[3][64 * 64];
    __shared__ unsigned short VL[3][64 * 64];

    int h = blockIdx.x;
    int kvh = h >> 2;
    int p = blockIdx.y;  // 0..15 -> strips (p, 31-p)
    int t = threadIdx.x, wave = t >> 6, lane = t & 63, lo = lane & 15, hi = lane >> 4;

    int srow = wave * 16 + (lane >> 3);
    int sc = lane & 7;
    int src1 = lo + ((hi & 1) << 5);
    bool selB = hi >= 2;
    int swz = lo & 7;
    int qrel = wave * 16 + lo;

#define STAGE_KV(buf, kb)                                                          \
    {                                                                              \
        _Pragma("unroll")                                                          \
        for (int j = 0; j < 2; j++) {                                              \
            int r = srow + j * 8;                                                  \
            gll16(Kr + (size_t)((kb) * 64 + r) * 512 + kvh * 64 +                  \
                      ((sc ^ (r & 7)) * 8),                                        \
                  &KL[buf][(wave * 16 + j * 8) * 64]);                             \
            gll16(Vt + (size_t)(kvh * 64 + r) * 2048 + (kb) * 64 +                 \
                      ((sc ^ (r & 7)) * 8),                                        \
                  &VL[buf][(wave * 16 + j * 8) * 64]);                             \
        }                                                                          \
    }

#pragma unroll 1
    for (int part = 0; part < 2; ++part) {
        int s = part ? (31 - p) : p;
        int qw = s * 64 + wave * 16;

        s16x8 qf[2];
#pragma unroll
        for (int hf = 0; hf < 2; hf++)
            qf[hf] = *(const s16x8*)(Q + (size_t)(qw + lo) * 2048 +
                                     h * 64 + hf * 32 + hi * 8);

        f32x4 O[4] = {};
        float m = -1e30f, l = 0.f;

        STAGE_KV(0, 0);
        STAGE_KV(1, (s > 0 ? 1 : 0));
        int cur = 0, sb = 2;

        for (int kb = 0; kb <= s; ++kb) {
            CBAR(4);
            int nx = (kb + 2 > s) ? s : kb + 2;
            STAGE_KV(sb, nx);

            s16x8 kf[4][2];
#pragma unroll
            for (int tt = 0; tt < 4; tt++)
#pragma unroll
                for (int hf = 0; hf < 2; hf++) {
                    int ch = (hf * 4 + hi) ^ swz;
                    kf[tt][hf] = *(const s16x8*)&KL[cur][(tt * 16 + lo) * 64 + ch * 8];
                }
            s16x8 vf[2][4];
#pragma unroll
            for (int c = 0; c < 2; c++)
#pragma unroll
                for (int dt = 0; dt < 4; dt++) {
                    int ch = (c * 4 + hi) ^ swz;
                    vf[c][dt] = *(const s16x8*)&VL[cur][(dt * 16 + lo) * 64 + ch * 8];
                }

            f32x4 s0[4];
            __builtin_amdgcn_s_setprio(1);
#pragma unroll
            for (int tt = 0; tt < 4; tt++) {
                f32x4 z0 = {};
                z0 = __builtin_amdgcn_mfma_f32_16x16x32_bf16(kf[tt][0], qf[0], z0, 0, 0, 0);
                z0 = __builtin_amdgcn_mfma_f32_16x16x32_bf16(kf[tt][1], qf[1], z0, 0, 0, 0);
                s0[tt] = z0;
            }
            __builtin_amdgcn_s_setprio(0);

            if (kb == s) {
#pragma unroll
                for (int tt = 0; tt < 4; tt++)
#pragma unroll
                    for (int r = 0; r < 4; r++) {
                        int kg = tt * 16 + hi * 4 + r;
                        if (kg > qrel) s0[tt][r] = -1e30f;
                    }
            }

            float mx = s0[0][0];
#pragma unroll
            for (int tt = 0; tt < 4; tt++)
#pragma unroll
                for (int r = 0; r < 4; r++) mx = fmaxf(mx, s0[tt][r]);
            mx = fmaxf(mx, __shfl_xor(mx, 16));
            mx = fmaxf(mx, __shfl_xor(mx, 32));

            if (!__all(mx - m <= 8.0f)) {
                float mn = fmaxf(m, mx);
                float al = __builtin_amdgcn_exp2f(m - mn);
                m = mn;
                l *= al;
                float alr[4];
#pragma unroll
                for (int r = 0; r < 4; r++) alr[r] = __shfl(al, hi * 4 + r);
#pragma unroll
                for (int dt = 0; dt < 4; dt++)
#pragma unroll
                    for (int r = 0; r < 4; r++) O[dt][r] *= alr[r];
            }

            unsigned int pk[4][2];
            float rs = 0.f;
#pragma unroll
            for (int tt = 0; tt < 4; tt++) {
#pragma unroll
                for (int r = 0; r < 4; r++) {
                    float pv = __builtin_amdgcn_exp2f(s0[tt][r] - m);
                    s0[tt][r] = pv;
                    rs += pv;
                }
                unsigned int a, b;
                asm("v_cvt_pk_bf16_f32 %0, %1, %2" : "=v"(a) : "v"(s0[tt][0]), "v"(s0[tt][1]));
                asm("v_cvt_pk_bf16_f32 %0, %1, %2" : "=v"(b) : "v"(s0[tt][2]), "v"(s0[tt][3]));
                pk[tt][0] = a; pk[tt][1] = b;
            }
            rs += __shfl_xor(rs, 16);
            rs += __shfl_xor(rs, 32);
            l += rs;

#pragma unroll
            for (int c = 0; c < 2; c++) {
                s16x8 pa = repack_p(pk, c, src1, selB);
                __builtin_amdgcn_s_setprio(1);
#pragma unroll
                for (int dt = 0; dt < 4; dt++)
                    O[dt] = __builtin_amdgcn_mfma_f32_16x16x32_bf16(pa, vf[c][dt], O[dt], 0, 0, 0);
                __builtin_amdgcn_s_setprio(0);
            }

            cur = (cur == 2) ? 0 : cur + 1;
            sb = (sb == 2) ? 0 : sb + 1;
        }

        asm volatile("s_waitcnt vmcnt(0)" ::: "memory");
        __builtin_amdgcn_s_barrier();
        asm volatile("" ::: "memory");

        float inv[4];
#pragma unroll
        for (int r = 0; r < 4; r++) inv[r] = 1.0f / __shfl(l, hi * 4 + r);
        int qrow = qw + hi * 4;
#pragma unroll
        for (int dt = 0; dt < 4; dt++)
#pragma unroll
            for (int r = 0; r < 4; r++)
                Oa[(size_t)(qrow + r) * 2048 + h * 64 + dt * 16 + lo] =
                    f2b(O[dt][r] * inv[r]);
    }
}

extern "C" void kernel_launch(void* const* d_in, const int* in_sizes, int n_in,
                              void* d_out, int out_size, void* d_ws, size_t ws_size,
                              hipStream_t stream) {
    const float* x  = (const float*)d_in[0];
    const float* R  = (const float*)d_in[1];
    // d_in[2] = mask: unused (causal mask applied analytically)
    const float* wq = (const float*)d_in[3];
    const float* wk = (const float*)d_in[4];
    const float* wv = (const float*)d_in[5];
    const float* wo = (const float*)d_in[6];

    float* out0 = (float*)d_out;
    float* outK = out0 + (size_t)2048 * 2048;
    float* outV = outK + (size_t)32 * 2048 * 64;

    char* ws = (char*)d_ws;
    unsigned short* BTall = (unsigned short*)(ws);               // 12 MB [3072][2048]
    unsigned short* woT = (unsigned short*)(ws + 12582912);      // 8 MB
    unsigned short* Qb  = (unsigned short*)(ws + 20971520);      // 8 MB
    unsigned short* Kb  = (unsigned short*)(ws + 29360128);      // 2 MB
    unsigned short* VtT = (unsigned short*)(ws + 33554432);      // 2 MB [512][2048]
    unsigned short* Ob  = (unsigned short*)(ws + 35651584);      // 8 MB
    float* cosT = (float*)(ws + 44040192);                       // 256 KB
    float* sinT = (float*)(ws + 44302336);                       // 256 KB
    unsigned short* xb  = (unsigned short*)(ws + 44564480);      // 8 MB

    prep<<<dim3(32, 32, 6), 256, 0, stream>>>(x, R, wq, wk, wv, wo, xb, BTall,
                                              woT, cosT, sinT);

    gemm_qkv<<<dim3(24, 32), 128, 0, stream>>>(xb, BTall, Qb, Kb, VtT, cosT, sinT, outK, outV);

    attn<<<dim3(32, 16), 256, 0, stream>>>(Qb, Kb, VtT, Ob);

    gemm_out<<<dim3(16, 32), 128, 0, stream>>>(Ob, woT, out0, 2048, 2048, 2048);
}